// Round 1
// baseline (390.160 us; speedup 1.0000x reference)
//
#include <hip/hip_runtime.h>
#include <math.h>

#define T_ 4
#define B_ 4
#define C_ 384
#define Hh 32
#define Ww 32
#define HW 1024
#define NH_ 12
#define Dh 32
#define C2_ 768
#define Np_ 256
#define EPS_ 1e-5f

// ---------------- K1: LIF over x -> xs (binary floats) ----------------
__global__ __launch_bounds__(256) void k_lif_x(const float* __restrict__ x,
                                               float* __restrict__ xs) {
    const int S = B_ * C_ * HW;            // 1,572,864
    int i4 = blockIdx.x * 256 + threadIdx.x;
    size_t base = (size_t)i4 * 4;
    float vx = 0.f, vy = 0.f, vz = 0.f, vw = 0.f;
#pragma unroll
    for (int t = 0; t < T_; ++t) {
        float4 xt = *(const float4*)(x + (size_t)t * S + base);
        vx += (xt.x - vx) * 0.5f;
        vy += (xt.y - vy) * 0.5f;
        vz += (xt.z - vz) * 0.5f;
        vw += (xt.w - vw) * 0.5f;
        float4 s;
        s.x = (vx >= 1.0f) ? 1.0f : 0.0f;  vx = (vx >= 1.0f) ? 0.f : vx;
        s.y = (vy >= 1.0f) ? 1.0f : 0.0f;  vy = (vy >= 1.0f) ? 0.f : vy;
        s.z = (vz >= 1.0f) ? 1.0f : 0.0f;  vz = (vz >= 1.0f) ? 0.f : vz;
        s.w = (vw >= 1.0f) ? 1.0f : 0.0f;  vw = (vw >= 1.0f) ? 0.f : vw;
        *(float4*)(xs + (size_t)t * S + base) = s;
    }
}

// ---------------- K2: patch conv (stride 2) + BN1 -> y1,y2 ----------------
// GEMM: M=768 (oc), K=1536 (ic*4+kh*2+kw), N=256 per tb (im2col of xs)
__global__ __launch_bounds__(256) void k_conv(const float* __restrict__ xs,
                                              const float* __restrict__ Wc,
                                              const float* __restrict__ g1,
                                              const float* __restrict__ b1,
                                              float* __restrict__ y1,
                                              float* __restrict__ y2) {
    __shared__ float As[32][68];   // [k][oc], padded
    __shared__ float Bs[32][68];   // [k][n],  padded
    const int tb = blockIdx.z;
    const int oc0 = blockIdx.y * 64;
    const int n0 = blockIdx.x * 64;
    const int tid = threadIdx.x;
    const int tx = tid & 15, ty = tid >> 4;
    float acc[4][4] = {{0.f}};

    for (int k0 = 0; k0 < 1536; k0 += 32) {
#pragma unroll
        for (int i = 0; i < 2; ++i) {       // A: 64 oc x 32 k
            int f4 = tid + i * 256;
            int row = f4 >> 3;              // 0..63
            int c4 = f4 & 7;                // 0..7
            float4 a = *(const float4*)(Wc + (size_t)(oc0 + row) * 1536 + k0 + c4 * 4);
            As[c4 * 4 + 0][row] = a.x;
            As[c4 * 4 + 1][row] = a.y;
            As[c4 * 4 + 2][row] = a.z;
            As[c4 * 4 + 3][row] = a.w;
        }
#pragma unroll
        for (int i = 0; i < 8; ++i) {       // B: im2col 32 k x 64 n
            int e = tid + i * 256;
            int nr = e & 63, kc = e >> 6;
            int k = k0 + kc;
            int ic = k >> 2, kh = (k >> 1) & 1, kw = k & 1;
            int n = n0 + nr;
            int ph = n >> 4, pw = n & 15;
            Bs[kc][nr] = xs[(((size_t)tb * C_ + ic) * Hh + 2 * ph + kh) * Ww + 2 * pw + kw];
        }
        __syncthreads();
#pragma unroll
        for (int kc = 0; kc < 32; ++kc) {
            float4 a4 = *(const float4*)&As[kc][ty * 4];
            float4 b4 = *(const float4*)&Bs[kc][tx * 4];
            acc[0][0] += a4.x * b4.x; acc[0][1] += a4.x * b4.y; acc[0][2] += a4.x * b4.z; acc[0][3] += a4.x * b4.w;
            acc[1][0] += a4.y * b4.x; acc[1][1] += a4.y * b4.y; acc[1][2] += a4.y * b4.z; acc[1][3] += a4.y * b4.w;
            acc[2][0] += a4.z * b4.x; acc[2][1] += a4.z * b4.y; acc[2][2] += a4.z * b4.z; acc[2][3] += a4.z * b4.w;
            acc[3][0] += a4.w * b4.x; acc[3][1] += a4.w * b4.y; acc[3][2] += a4.w * b4.z; acc[3][3] += a4.w * b4.w;
        }
        __syncthreads();
    }
    const float rs = 1.0f / sqrtf(1.0f + EPS_);
#pragma unroll
    for (int qa = 0; qa < 4; ++qa) {
        int oc = oc0 + ty * 4 + qa;
        int h = oc >> 6, r = oc & 63;
        float bn = g1[oc] * rs, be = b1[oc];
        float* dst = (r < 32) ? y1 : y2;
        int d = r & 31;
        int g = tb * NH_ + h;
        float4 o;
        o.x = acc[qa][0] * bn + be;
        o.y = acc[qa][1] * bn + be;
        o.z = acc[qa][2] * bn + be;
        o.w = acc[qa][3] * bn + be;
        *(float4*)(dst + ((size_t)g * Dh + d) * Np_ + n0 + tx * 4) = o;
    }
}

// ---------------- K3: fused attention (ein1 -> LIF -> sparse ein2 -> LIF) ----------------
// grid (32 m-tiles, 12 heads, 4 batch); 256 threads; thread = n for phase A.
__global__ __launch_bounds__(256) void k_attn(const float* __restrict__ xs,
                                              const float* __restrict__ y1,
                                              const float* __restrict__ y2,
                                              const float* __restrict__ frx,
                                              const float* __restrict__ fra,
                                              float* __restrict__ obin) {
    __shared__ float xbF[32][36];     // [d][j] xs bits for this m-tile (padded, 16B-aligned rows)
    __shared__ float outAcc[32][33];  // [d][j] ein2 accumulator
    const int m0 = blockIdx.x * 32;
    const int h = blockIdx.y;
    const int b = blockIdx.z;
    const int tid = threadIdx.x;
    const float s1 = 1.0f / sqrtf(frx[h] * 32.0f);
    const float s2 = 1.0f / sqrtf(fra[h] * 256.0f);
    float v_attn[32];
#pragma unroll
    for (int j = 0; j < 32; ++j) v_attn[j] = 0.f;
    float v_out[4] = {0.f, 0.f, 0.f, 0.f};
    const int od = tid >> 3;          // out-phase d
    const int oj = (tid & 7) * 4;     // out-phase j base

    for (int t = 0; t < T_; ++t) {
        const int tb = t * B_ + b;
        const size_t gbase = ((size_t)tb * NH_ + h) * (Dh * Np_);
        const size_t xsbase = ((size_t)tb * C_ + h * Dh) * HW;
#pragma unroll
        for (int i = 0; i < 4; ++i) {   // stage bits + zero accumulator
            int e = tid + i * 256;
            int d = e >> 5, j = e & 31;
            xbF[d][j] = xs[xsbase + (size_t)d * HW + m0 + j];
            outAcc[d][j] = 0.f;
        }
        __syncthreads();
        float acc[32];
#pragma unroll
        for (int j = 0; j < 32; ++j) acc[j] = 0.f;
#pragma unroll 4
        for (int d = 0; d < 32; ++d) {
            float y1v = y1[gbase + d * Np_ + tid];
#pragma unroll
            for (int jq = 0; jq < 8; ++jq) {
                float4 xb4 = *(const float4*)&xbF[d][jq * 4];
                acc[jq * 4 + 0] += y1v * xb4.x;
                acc[jq * 4 + 1] += y1v * xb4.y;
                acc[jq * 4 + 2] += y1v * xb4.z;
                acc[jq * 4 + 3] += y1v * xb4.w;
            }
        }
        unsigned mask = 0u;
#pragma unroll
        for (int j = 0; j < 32; ++j) {   // attn LIF (thread owns row n=tid, 32 cols)
            float v = v_attn[j];
            v += (acc[j] * s1 - v) * 0.5f;
            if (v >= 1.0f) { mask |= (1u << j); v = 0.f; }
            v_attn[j] = v;
        }
        // sparse ein2: for each attn spike (n=tid, j), add y2[:,n] into outAcc[:,j]
        while (mask) {
            int j = __ffs(mask) - 1;
            mask &= mask - 1;
            for (int d = 0; d < 32; ++d)
                atomicAdd(&outAcc[d][j], y2[gbase + d * Np_ + tid]);
        }
        __syncthreads();
        // out LIF: thread owns (od, oj..oj+3)
        float ob[4];
#pragma unroll
        for (int q = 0; q < 4; ++q) {
            float o = outAcc[od][oj + q] * s2;
            float v = v_out[q];
            v += (o - v) * 0.5f;
            bool sp = (v >= 1.0f);
            ob[q] = sp ? 1.0f : 0.0f;
            v_out[q] = sp ? 0.f : v;
        }
        float4 o4 = make_float4(ob[0], ob[1], ob[2], ob[3]);
        *(float4*)(obin + ((size_t)tb * C_ + h * Dh + od) * HW + m0 + oj) = o4;
        __syncthreads();   // protect outAcc/xbF before next t
    }
}

// ---------------- K4: projection GEMM + BN2 + residual ----------------
// per tb: M=384 (o), K=384 (c), N=1024 (m)
__global__ __launch_bounds__(256) void k_proj(const float* __restrict__ obin,
                                              const float* __restrict__ Wp,
                                              const float* __restrict__ g2,
                                              const float* __restrict__ b2,
                                              const float* __restrict__ x,
                                              float* __restrict__ out) {
    __shared__ float As[32][68];   // [k][o]
    __shared__ float Bs[32][68];   // [k][n]
    const int tb = blockIdx.z;
    const int o0 = blockIdx.y * 64;
    const int n0 = blockIdx.x * 64;
    const int tid = threadIdx.x;
    const int tx = tid & 15, ty = tid >> 4;
    float acc[4][4] = {{0.f}};

    for (int k0 = 0; k0 < C_; k0 += 32) {
#pragma unroll
        for (int i = 0; i < 2; ++i) {
            int f4 = tid + i * 256;
            int row = f4 >> 3, c4 = f4 & 7;
            float4 a = *(const float4*)(Wp + (size_t)(o0 + row) * C_ + k0 + c4 * 4);
            As[c4 * 4 + 0][row] = a.x;
            As[c4 * 4 + 1][row] = a.y;
            As[c4 * 4 + 2][row] = a.z;
            As[c4 * 4 + 3][row] = a.w;
        }
#pragma unroll
        for (int i = 0; i < 2; ++i) {
            int f4 = tid + i * 256;           // 512 float4 = 32k x 64n
            int kc = f4 >> 4, n4 = (f4 & 15) * 4;
            float4 bv = *(const float4*)(obin + ((size_t)tb * C_ + k0 + kc) * HW + n0 + n4);
            *(float4*)&Bs[kc][n4] = bv;
        }
        __syncthreads();
#pragma unroll
        for (int kc = 0; kc < 32; ++kc) {
            float4 a4 = *(const float4*)&As[kc][ty * 4];
            float4 b4 = *(const float4*)&Bs[kc][tx * 4];
            acc[0][0] += a4.x * b4.x; acc[0][1] += a4.x * b4.y; acc[0][2] += a4.x * b4.z; acc[0][3] += a4.x * b4.w;
            acc[1][0] += a4.y * b4.x; acc[1][1] += a4.y * b4.y; acc[1][2] += a4.y * b4.z; acc[1][3] += a4.y * b4.w;
            acc[2][0] += a4.z * b4.x; acc[2][1] += a4.z * b4.y; acc[2][2] += a4.z * b4.z; acc[2][3] += a4.z * b4.w;
            acc[3][0] += a4.w * b4.x; acc[3][1] += a4.w * b4.y; acc[3][2] += a4.w * b4.z; acc[3][3] += a4.w * b4.w;
        }
        __syncthreads();
    }
    const float rs = 1.0f / sqrtf(1.0f + EPS_);
#pragma unroll
    for (int qa = 0; qa < 4; ++qa) {
        int o = o0 + ty * 4 + qa;
        float bn = g2[o] * rs, be = b2[o];
        size_t idx = ((size_t)tb * C_ + o) * HW + n0 + tx * 4;
        float4 xv = *(const float4*)(x + idx);
        float4 r;
        r.x = acc[qa][0] * bn + be + xv.x;
        r.y = acc[qa][1] * bn + be + xv.y;
        r.z = acc[qa][2] * bn + be + xv.z;
        r.w = acc[qa][3] * bn + be + xv.w;
        *(float4*)(out + idx) = r;
    }
}

extern "C" void kernel_launch(void* const* d_in, const int* in_sizes, int n_in,
                              void* d_out, int out_size, void* d_ws, size_t ws_size,
                              hipStream_t stream) {
    const float* x      = (const float*)d_in[0];
    const float* Wconv  = (const float*)d_in[1];
    const float* gamma1 = (const float*)d_in[2];
    const float* beta1  = (const float*)d_in[3];
    const float* Wproj  = (const float*)d_in[4];
    const float* gamma2 = (const float*)d_in[5];
    const float* beta2  = (const float*)d_in[6];
    const float* frx    = (const float*)d_in[7];
    const float* fra    = (const float*)d_in[8];
    float* out = (float*)d_out;

    float* ws   = (float*)d_ws;
    float* xs   = ws;                      // 6,291,456 floats
    float* y1   = ws + 6291456;            // 1,572,864
    float* y2   = ws + 7864320;            // 1,572,864
    float* obin = ws + 9437184;            // 6,291,456  (end: 15,728,640 floats = 62.9 MB)

    k_lif_x<<<1536, 256, 0, stream>>>(x, xs);
    k_conv<<<dim3(4, 12, 16), 256, 0, stream>>>(xs, Wconv, gamma1, beta1, y1, y2);
    k_attn<<<dim3(32, 12, 4), 256, 0, stream>>>(xs, y1, y2, frx, fra, obin);
    k_proj<<<dim3(16, 6, 16), 256, 0, stream>>>(obin, Wproj, gamma2, beta2, x, out);
}

// Round 2
// 315.943 us; speedup vs baseline: 1.2349x; 1.2349x over previous
//
#include <hip/hip_runtime.h>
#include <hip/hip_bf16.h>
#include <math.h>

// R2: conv & proj GEMMs -> bf16 MFMA with 3-way weight split (fp32-accurate).
//   - k_lif_im2col: LIF(x) fused with im2col, writes Bconv[n][k] bf16 (binary exact)
//   - k_wsplit: W = bf16(hi)+bf16(mid)+bf16(lo), residual ~2^-24 rel
//   - k_mconv / k_mproj: 64x128 tile, 4 waves, mfma_f32_16x16x32_bf16, 3 splits
//   - k_attn: unchanged math; reads bits from Bconv, writes obin_t[n][c] bf16

typedef __attribute__((ext_vector_type(8))) short short8;
typedef __attribute__((ext_vector_type(4))) float f32x4;

#define T_ 4
#define B_ 4
#define C_ 384
#define HW 1024
#define NH_ 12
#define Np_ 256
#define EPS_ 1e-5f
#define LDK 56   // LDS row stride (elems) for K=32 tiles: 112B, 16B-aligned, conflict-light

static __device__ __forceinline__ unsigned short f2bf(float f) {
    __hip_bfloat16 h = __float2bfloat16(f);
    return *reinterpret_cast<unsigned short*>(&h);
}
static __device__ __forceinline__ float bf2f(unsigned short u) {
    __hip_bfloat16 h = *reinterpret_cast<__hip_bfloat16*>(&u);
    return __bfloat162float(h);
}

// ---------------- K0: weight 3-way bf16 split ----------------
__global__ __launch_bounds__(256) void k_wsplit(const float* __restrict__ Wc,
                                                const float* __restrict__ Wp,
                                                unsigned short* __restrict__ Wc3,
                                                unsigned short* __restrict__ Wp3) {
    const int NC = 768 * 1536;
    const int NP = 384 * 384;
    int i = blockIdx.x * 256 + threadIdx.x;
    float w; unsigned short* dst; int idx, plane;
    if (i < NC) { w = Wc[i]; dst = Wc3; idx = i; plane = NC; }
    else {
        int j = i - NC;
        if (j >= NP) return;
        w = Wp[j]; dst = Wp3; idx = j; plane = NP;
    }
    unsigned short u0 = f2bf(w);  float f0 = bf2f(u0);
    float r1 = w - f0;
    unsigned short u1 = f2bf(r1); float f1 = bf2f(u1);
    float r2 = r1 - f1;
    unsigned short u2 = f2bf(r2);
    dst[idx] = u0; dst[plane + idx] = u1; dst[2 * plane + idx] = u2;
}

// ---------------- K1: LIF over x fused with im2col -> Bconv[n][k] bf16 ----------------
// thread = (b, c, ph, pw); owns the 2x2 input patch; k = 4c+2kh+kw; n = tb*256+ph*16+pw
__global__ __launch_bounds__(256) void k_lif_im2col(const float* __restrict__ x,
                                                    unsigned short* __restrict__ Bc) {
    int gt = blockIdx.x * 256 + threadIdx.x;   // 0..393215
    int pw = gt & 15, ph = (gt >> 4) & 15;
    int v = gt >> 8;                            // 0..1535
    int c = v % 384, b = v / 384;
    float v00 = 0.f, v01 = 0.f, v10 = 0.f, v11 = 0.f;
    const size_t xrow = ((size_t)b * C_ + c) * HW + (size_t)(2 * ph) * 32 + 2 * pw;
#pragma unroll
    for (int t = 0; t < T_; ++t) {
        const float* px = x + (size_t)t * (B_ * C_ * HW) + xrow;
        float2 r0 = *(const float2*)px;
        float2 r1 = *(const float2*)(px + 32);
        v00 += (r0.x - v00) * 0.5f;
        v01 += (r0.y - v01) * 0.5f;
        v10 += (r1.x - v10) * 0.5f;
        v11 += (r1.y - v11) * 0.5f;
        ushort4 s;
        s.x = (v00 >= 1.f) ? 0x3F80 : 0; if (v00 >= 1.f) v00 = 0.f;
        s.y = (v01 >= 1.f) ? 0x3F80 : 0; if (v01 >= 1.f) v01 = 0.f;
        s.z = (v10 >= 1.f) ? 0x3F80 : 0; if (v10 >= 1.f) v10 = 0.f;
        s.w = (v11 >= 1.f) ? 0x3F80 : 0; if (v11 >= 1.f) v11 = 0.f;
        int n = (t * B_ + b) * 256 + ph * 16 + pw;
        *(ushort4*)(Bc + (size_t)n * 1536 + 4 * c) = s;
    }
}

// ---------------- K2: conv GEMM via MFMA (M=768,K=1536,N=4096, 3 splits) ----------------
__global__ __launch_bounds__(256) void k_mconv(const unsigned short* __restrict__ Bc,
                                               const unsigned short* __restrict__ Wc3,
                                               const float* __restrict__ g1,
                                               const float* __restrict__ b1,
                                               float* __restrict__ y1,
                                               float* __restrict__ y2) {
    __shared__ short As[3][64][LDK];
    __shared__ short Bs[128][LDK];
    const int nb = blockIdx.x, mb = blockIdx.y;
    const int tid = threadIdx.x;
    const int lane = tid & 63, wave = tid >> 6;
    const int wm = wave >> 1, wn = wave & 1;
    const int quad = lane >> 4, lr = lane & 15;
    const int arow = tid >> 2, akoff = (tid & 3) * 8;
    f32x4 acc[2][4];
#pragma unroll
    for (int im = 0; im < 2; ++im)
#pragma unroll
        for (int in = 0; in < 4; ++in)
            acc[im][in] = (f32x4){0.f, 0.f, 0.f, 0.f};

    for (int k0 = 0; k0 < 1536; k0 += 32) {
#pragma unroll
        for (int s = 0; s < 3; ++s) {
            short8 a = *(const short8*)(Wc3 + ((size_t)(s * 768 + mb * 64 + arow)) * 1536 + k0 + akoff);
            *(short8*)&As[s][arow][akoff] = a;
        }
#pragma unroll
        for (int i = 0; i < 2; ++i) {
            int f = i * 256 + tid;
            int row = f >> 2, koff = (f & 3) * 8;
            short8 bv = *(const short8*)(Bc + ((size_t)(nb * 128 + row)) * 1536 + k0 + koff);
            *(short8*)&Bs[row][koff] = bv;
        }
        __syncthreads();
        short8 bf[4], af[3][2];
#pragma unroll
        for (int in = 0; in < 4; ++in)
            bf[in] = *(const short8*)&Bs[wn * 64 + in * 16 + lr][quad * 8];
#pragma unroll
        for (int s = 0; s < 3; ++s)
#pragma unroll
            for (int im = 0; im < 2; ++im)
                af[s][im] = *(const short8*)&As[s][wm * 32 + im * 16 + lr][quad * 8];
#pragma unroll
        for (int s = 0; s < 3; ++s)
#pragma unroll
            for (int im = 0; im < 2; ++im)
#pragma unroll
                for (int in = 0; in < 4; ++in)
                    acc[im][in] = __builtin_amdgcn_mfma_f32_16x16x32_bf16(af[s][im], bf[in], acc[im][in], 0, 0, 0);
        __syncthreads();
    }
    const float rs = 1.0f / sqrtf(1.0f + EPS_);
#pragma unroll
    for (int im = 0; im < 2; ++im) {
#pragma unroll
        for (int in = 0; in < 4; ++in) {
            int n_g = nb * 128 + wn * 64 + in * 16 + lr;
            int tb = n_g >> 8, pn = n_g & 255;
#pragma unroll
            for (int r = 0; r < 4; ++r) {
                int oc = mb * 64 + wm * 32 + im * 16 + quad * 4 + r;
                float val = acc[im][in][r] * (g1[oc] * rs) + b1[oc];
                int hh = oc >> 6, rr = oc & 63;
                float* dst = (rr < 32) ? y1 : y2;
                dst[((size_t)(tb * NH_ + hh) * 32 + (rr & 31)) * 256 + pn] = val;
            }
        }
    }
}

// ---------------- K3: fused attention (ein1 -> LIF -> sparse ein2 -> LIF) ----------------
__global__ __launch_bounds__(256) void k_attn(const unsigned short* __restrict__ Bc,
                                              const float* __restrict__ y1,
                                              const float* __restrict__ y2,
                                              const float* __restrict__ frx,
                                              const float* __restrict__ fra,
                                              unsigned short* __restrict__ obt) {
    __shared__ float xbF[32][36];
    __shared__ float outAcc[32][33];
    const int m0 = blockIdx.x * 32;
    const int hh = blockIdx.y;
    const int b = blockIdx.z;
    const int tid = threadIdx.x;
    const float s1 = 1.0f / sqrtf(frx[hh] * 32.0f);
    const float s2 = 1.0f / sqrtf(fra[hh] * 256.0f);
    const int sr = m0 >> 5;   // spatial row (H=W=32, m-tile spans exactly one row)
    float v_attn[32];
#pragma unroll
    for (int j = 0; j < 32; ++j) v_attn[j] = 0.f;
    float v_out[4] = {0.f, 0.f, 0.f, 0.f};
    const int od = tid >> 3;
    const int oj = (tid & 7) * 4;

    for (int t = 0; t < T_; ++t) {
        const int tb = t * B_ + b;
        const size_t gbase = ((size_t)tb * NH_ + hh) * (32 * Np_);
#pragma unroll
        for (int i = 0; i < 4; ++i) {   // stage xs bits (from Bconv) + zero accumulator
            int e = tid + i * 256;
            int d = e >> 5, j = e & 31;
            int n = tb * 256 + (sr >> 1) * 16 + (j >> 1);
            int k = 4 * (hh * 32 + d) + 2 * (sr & 1) + (j & 1);
            xbF[d][j] = bf2f(Bc[(size_t)n * 1536 + k]);
            outAcc[d][j] = 0.f;
        }
        __syncthreads();
        float acc[32];
#pragma unroll
        for (int j = 0; j < 32; ++j) acc[j] = 0.f;
#pragma unroll 4
        for (int d = 0; d < 32; ++d) {
            float y1v = y1[gbase + d * Np_ + tid];
#pragma unroll
            for (int jq = 0; jq < 8; ++jq) {
                float4 xb4 = *(const float4*)&xbF[d][jq * 4];
                acc[jq * 4 + 0] += y1v * xb4.x;
                acc[jq * 4 + 1] += y1v * xb4.y;
                acc[jq * 4 + 2] += y1v * xb4.z;
                acc[jq * 4 + 3] += y1v * xb4.w;
            }
        }
        unsigned mask = 0u;
#pragma unroll
        for (int j = 0; j < 32; ++j) {
            float v = v_attn[j];
            v += (acc[j] * s1 - v) * 0.5f;
            if (v >= 1.0f) { mask |= (1u << j); v = 0.f; }
            v_attn[j] = v;
        }
        while (mask) {
            int j = __ffs(mask) - 1;
            mask &= mask - 1;
            for (int d = 0; d < 32; ++d)
                atomicAdd(&outAcc[d][j], y2[gbase + d * Np_ + tid]);
        }
        __syncthreads();
#pragma unroll
        for (int q = 0; q < 4; ++q) {
            float o = outAcc[od][oj + q] * s2;
            float v = v_out[q];
            v += (o - v) * 0.5f;
            bool sp = (v >= 1.0f);
            v_out[q] = sp ? 0.f : v;
            // obin transposed: [tb][pos][ch] bf16 (k-contiguous rows for proj B-frags)
            obt[((size_t)tb * HW + (m0 + oj + q)) * C_ + hh * 32 + od] = sp ? 0x3F80 : 0;
        }
        __syncthreads();
    }
}

// ---------------- K4: proj GEMM via MFMA (M=384,K=384,N=16384, 3 splits) + BN2 + residual ----
__global__ __launch_bounds__(256) void k_mproj(const unsigned short* __restrict__ obt,
                                               const unsigned short* __restrict__ Wp3,
                                               const float* __restrict__ g2,
                                               const float* __restrict__ b2,
                                               const float* __restrict__ x,
                                               float* __restrict__ out) {
    __shared__ short As[3][64][LDK];
    __shared__ short Bs[128][LDK];
    const int nb = blockIdx.x, mb = blockIdx.y;   // nb<128, mb<6
    const int tid = threadIdx.x;
    const int lane = tid & 63, wave = tid >> 6;
    const int wm = wave >> 1, wn = wave & 1;
    const int quad = lane >> 4, lr = lane & 15;
    const int arow = tid >> 2, akoff = (tid & 3) * 8;
    f32x4 acc[2][4];
#pragma unroll
    for (int im = 0; im < 2; ++im)
#pragma unroll
        for (int in = 0; in < 4; ++in)
            acc[im][in] = (f32x4){0.f, 0.f, 0.f, 0.f};

    for (int k0 = 0; k0 < 384; k0 += 32) {
#pragma unroll
        for (int s = 0; s < 3; ++s) {
            short8 a = *(const short8*)(Wp3 + ((size_t)(s * 384 + mb * 64 + arow)) * 384 + k0 + akoff);
            *(short8*)&As[s][arow][akoff] = a;
        }
#pragma unroll
        for (int i = 0; i < 2; ++i) {
            int f = i * 256 + tid;
            int row = f >> 2, koff = (f & 3) * 8;
            short8 bv = *(const short8*)(obt + ((size_t)(nb * 128 + row)) * 384 + k0 + koff);
            *(short8*)&Bs[row][koff] = bv;
        }
        __syncthreads();
        short8 bf[4], af[3][2];
#pragma unroll
        for (int in = 0; in < 4; ++in)
            bf[in] = *(const short8*)&Bs[wn * 64 + in * 16 + lr][quad * 8];
#pragma unroll
        for (int s = 0; s < 3; ++s)
#pragma unroll
            for (int im = 0; im < 2; ++im)
                af[s][im] = *(const short8*)&As[s][wm * 32 + im * 16 + lr][quad * 8];
#pragma unroll
        for (int s = 0; s < 3; ++s)
#pragma unroll
            for (int im = 0; im < 2; ++im)
#pragma unroll
                for (int in = 0; in < 4; ++in)
                    acc[im][in] = __builtin_amdgcn_mfma_f32_16x16x32_bf16(af[s][im], bf[in], acc[im][in], 0, 0, 0);
        __syncthreads();
    }
    const float rs = 1.0f / sqrtf(1.0f + EPS_);
#pragma unroll
    for (int im = 0; im < 2; ++im) {
#pragma unroll
        for (int in = 0; in < 4; ++in) {
            int n_g = nb * 128 + wn * 64 + in * 16 + lr;   // = tb*1024 + hw
            int tb = n_g >> 10, hw = n_g & 1023;
#pragma unroll
            for (int r = 0; r < 4; ++r) {
                int o = mb * 64 + wm * 32 + im * 16 + quad * 4 + r;
                size_t idx = ((size_t)tb * C_ + o) * HW + hw;
                out[idx] = acc[im][in][r] * (g2[o] * rs) + b2[o] + x[idx];
            }
        }
    }
}

extern "C" void kernel_launch(void* const* d_in, const int* in_sizes, int n_in,
                              void* d_out, int out_size, void* d_ws, size_t ws_size,
                              hipStream_t stream) {
    const float* x      = (const float*)d_in[0];
    const float* Wconv  = (const float*)d_in[1];
    const float* gamma1 = (const float*)d_in[2];
    const float* beta1  = (const float*)d_in[3];
    const float* Wproj  = (const float*)d_in[4];
    const float* gamma2 = (const float*)d_in[5];
    const float* beta2  = (const float*)d_in[6];
    const float* frx    = (const float*)d_in[7];
    const float* fra    = (const float*)d_in[8];
    float* out = (float*)d_out;

    unsigned short* ws16 = (unsigned short*)d_ws;
    unsigned short* Bc  = ws16;                 // 4096*1536      = 6,291,456 u16
    unsigned short* Wc3 = ws16 + 6291456;       // 3*768*1536     = 3,538,944 u16
    unsigned short* Wp3 = ws16 + 9830400;       // 3*384*384     = 442,368 u16
    unsigned short* obt = ws16 + 10272768;      // 16*1024*384    = 6,291,456 u16
    float* y1 = (float*)(ws16 + 16564224);      // 1,572,864 f32
    float* y2 = y1 + 1572864;                   // 1,572,864 f32  (end ~45.7 MB)

    k_wsplit<<<5184, 256, 0, stream>>>(Wconv, Wproj, Wc3, Wp3);
    k_lif_im2col<<<1536, 256, 0, stream>>>(x, Bc);
    k_mconv<<<dim3(32, 12), 256, 0, stream>>>(Bc, Wc3, gamma1, beta1, y1, y2);
    k_attn<<<dim3(32, 12, 4), 256, 0, stream>>>(Bc, y1, y2, frx, fra, obt);
    k_mproj<<<dim3(128, 6), 256, 0, stream>>>(obt, Wp3, gamma2, beta2, x, out);
}

// Round 3
// 275.413 us; speedup vs baseline: 1.4166x; 1.1472x over previous
//
#include <hip/hip_runtime.h>
#include <hip/hip_bf16.h>
#include <math.h>

// R3: attention einsums -> MFMA.
//   ein1 (y1^T·xs) and ein2 (y2·attn) both have a binary bf16-exact operand.
//   y1/y2 are emitted pre-scaled + 3-way bf16 split by k_mconv's epilogue.
//   attn spikes round-trip through LDS in ein2's B-fragment layout.

typedef __attribute__((ext_vector_type(8))) short short8;
typedef __attribute__((ext_vector_type(4))) float f32x4;

#define T_ 4
#define B_ 4
#define C_ 384
#define HW 1024
#define NH_ 12
#define Np_ 256
#define EPS_ 1e-5f
#define LDK 56

static __device__ __forceinline__ unsigned short f2bf(float f) {
    __hip_bfloat16 h = __float2bfloat16(f);
    return *reinterpret_cast<unsigned short*>(&h);
}
static __device__ __forceinline__ float bf2f(unsigned short u) {
    __hip_bfloat16 h = *reinterpret_cast<__hip_bfloat16*>(&u);
    return __bfloat162float(h);
}
static __device__ __forceinline__ void split3(float w, unsigned short& u0,
                                              unsigned short& u1, unsigned short& u2) {
    u0 = f2bf(w);  float f0 = bf2f(u0);
    float r1 = w - f0;
    u1 = f2bf(r1); float f1 = bf2f(u1);
    u2 = f2bf(r1 - f1);
}

// ---------------- K0: weight 3-way bf16 split ----------------
__global__ __launch_bounds__(256) void k_wsplit(const float* __restrict__ Wc,
                                                const float* __restrict__ Wp,
                                                unsigned short* __restrict__ Wc3,
                                                unsigned short* __restrict__ Wp3) {
    const int NC = 768 * 1536;
    const int NP = 384 * 384;
    int i = blockIdx.x * 256 + threadIdx.x;
    float w; unsigned short* dst; int idx, plane;
    if (i < NC) { w = Wc[i]; dst = Wc3; idx = i; plane = NC; }
    else {
        int j = i - NC;
        if (j >= NP) return;
        w = Wp[j]; dst = Wp3; idx = j; plane = NP;
    }
    unsigned short u0, u1, u2;
    split3(w, u0, u1, u2);
    dst[idx] = u0; dst[plane + idx] = u1; dst[2 * plane + idx] = u2;
}

// ---------------- K1: LIF(x) fused with im2col -> Bc[n][k] bf16, + xsb[tb][c][hw] bf16 ----
__global__ __launch_bounds__(256) void k_lif_im2col(const float* __restrict__ x,
                                                    unsigned short* __restrict__ Bc,
                                                    unsigned short* __restrict__ xsb) {
    int gt = blockIdx.x * 256 + threadIdx.x;
    int pw = gt & 15, ph = (gt >> 4) & 15;
    int v = gt >> 8;
    int c = v % 384, b = v / 384;
    float v00 = 0.f, v01 = 0.f, v10 = 0.f, v11 = 0.f;
    const size_t xrow = ((size_t)b * C_ + c) * HW + (size_t)(2 * ph) * 32 + 2 * pw;
#pragma unroll
    for (int t = 0; t < T_; ++t) {
        const float* px = x + (size_t)t * (B_ * C_ * HW) + xrow;
        float2 r0 = *(const float2*)px;
        float2 r1 = *(const float2*)(px + 32);
        v00 += (r0.x - v00) * 0.5f;
        v01 += (r0.y - v01) * 0.5f;
        v10 += (r1.x - v10) * 0.5f;
        v11 += (r1.y - v11) * 0.5f;
        ushort4 s;
        s.x = (v00 >= 1.f) ? 0x3F80 : 0; if (v00 >= 1.f) v00 = 0.f;
        s.y = (v01 >= 1.f) ? 0x3F80 : 0; if (v01 >= 1.f) v01 = 0.f;
        s.z = (v10 >= 1.f) ? 0x3F80 : 0; if (v10 >= 1.f) v10 = 0.f;
        s.w = (v11 >= 1.f) ? 0x3F80 : 0; if (v11 >= 1.f) v11 = 0.f;
        int tb = t * B_ + b;
        int n = tb * 256 + ph * 16 + pw;
        *(ushort4*)(Bc + (size_t)n * 1536 + 4 * c) = s;
        size_t xo = ((size_t)tb * C_ + c) * HW + (size_t)(2 * ph) * 32 + 2 * pw;
        ushort2 w0 = {s.x, s.y}, w1 = {s.z, s.w};
        *(ushort2*)(xsb + xo) = w0;
        *(ushort2*)(xsb + xo + 32) = w1;
    }
}

// ---------------- K2: conv GEMM via MFMA; epilogue emits scaled 3-split y1s/y2s ----------
// y1s: [tbh][s][n=256][d=32]  (ein1 A-operand rows)
// y2s: [tbh][s][d=32][n=256]  (ein2 A-operand rows)
__global__ __launch_bounds__(256) void k_mconv(const unsigned short* __restrict__ Bc,
                                               const unsigned short* __restrict__ Wc3,
                                               const float* __restrict__ g1,
                                               const float* __restrict__ b1,
                                               const float* __restrict__ frx,
                                               const float* __restrict__ fra,
                                               unsigned short* __restrict__ y1s,
                                               unsigned short* __restrict__ y2s) {
    __shared__ short As[3][64][LDK];
    __shared__ short Bs[128][LDK];
    const int nb = blockIdx.x, mb = blockIdx.y;
    const int tid = threadIdx.x;
    const int lane = tid & 63, wave = tid >> 6;
    const int wm = wave >> 1, wn = wave & 1;
    const int quad = lane >> 4, lr = lane & 15;
    const int arow = tid >> 2, akoff = (tid & 3) * 8;
    f32x4 acc[2][4];
#pragma unroll
    for (int im = 0; im < 2; ++im)
#pragma unroll
        for (int in = 0; in < 4; ++in)
            acc[im][in] = (f32x4){0.f, 0.f, 0.f, 0.f};

    for (int k0 = 0; k0 < 1536; k0 += 32) {
#pragma unroll
        for (int s = 0; s < 3; ++s) {
            short8 a = *(const short8*)(Wc3 + ((size_t)(s * 768 + mb * 64 + arow)) * 1536 + k0 + akoff);
            *(short8*)&As[s][arow][akoff] = a;
        }
#pragma unroll
        for (int i = 0; i < 2; ++i) {
            int f = i * 256 + tid;
            int row = f >> 2, koff = (f & 3) * 8;
            short8 bv = *(const short8*)(Bc + ((size_t)(nb * 128 + row)) * 1536 + k0 + koff);
            *(short8*)&Bs[row][koff] = bv;
        }
        __syncthreads();
        short8 bf[4], af[3][2];
#pragma unroll
        for (int in = 0; in < 4; ++in)
            bf[in] = *(const short8*)&Bs[wn * 64 + in * 16 + lr][quad * 8];
#pragma unroll
        for (int s = 0; s < 3; ++s)
#pragma unroll
            for (int im = 0; im < 2; ++im)
                af[s][im] = *(const short8*)&As[s][wm * 32 + im * 16 + lr][quad * 8];
#pragma unroll
        for (int s = 0; s < 3; ++s)
#pragma unroll
            for (int im = 0; im < 2; ++im)
#pragma unroll
                for (int in = 0; in < 4; ++in)
                    acc[im][in] = __builtin_amdgcn_mfma_f32_16x16x32_bf16(af[s][im], bf[in], acc[im][in], 0, 0, 0);
        __syncthreads();
    }
    const float rs = 1.0f / sqrtf(1.0f + EPS_);
    const int h = mb;                       // oc>>6 == mb (M=768 = 12h * 64)
    const float scl = (wm == 0) ? (1.0f / sqrtf(frx[h] * 32.0f))
                                : (1.0f / sqrtf(fra[h] * 256.0f));
    unsigned short* dst = (wm == 0) ? y1s : y2s;
#pragma unroll
    for (int im = 0; im < 2; ++im) {
#pragma unroll
        for (int in = 0; in < 4; ++in) {
            int n_g = nb * 128 + wn * 64 + in * 16 + lr;
            int tb = n_g >> 8, pn = n_g & 255;
            size_t base = (size_t)(tb * NH_ + h) * 3 * 8192;
            ushort4 o0, o1, o2;
#pragma unroll
            for (int r = 0; r < 4; ++r) {
                int oc = mb * 64 + wm * 32 + im * 16 + quad * 4 + r;
                float val = (acc[im][in][r] * (g1[oc] * rs) + b1[oc]) * scl;
                unsigned short u0, u1, u2;
                split3(val, u0, u1, u2);
                ((unsigned short*)&o0)[r] = u0;
                ((unsigned short*)&o1)[r] = u1;
                ((unsigned short*)&o2)[r] = u2;
            }
            int dd = im * 16 + quad * 4;    // d within [0,32)
            if (wm == 0) {
                *(ushort4*)&dst[base + 0 * 8192 + (size_t)pn * 32 + dd] = o0;
                *(ushort4*)&dst[base + 1 * 8192 + (size_t)pn * 32 + dd] = o1;
                *(ushort4*)&dst[base + 2 * 8192 + (size_t)pn * 32 + dd] = o2;
            } else {
#pragma unroll
                for (int r = 0; r < 4; ++r) {
                    dst[base + 0 * 8192 + (size_t)(dd + r) * 256 + pn] = ((unsigned short*)&o0)[r];
                    dst[base + 1 * 8192 + (size_t)(dd + r) * 256 + pn] = ((unsigned short*)&o1)[r];
                    dst[base + 2 * 8192 + (size_t)(dd + r) * 256 + pn] = ((unsigned short*)&o2)[r];
                }
            }
        }
    }
}

// ---------------- K3: fused attention, all-MFMA ----------------
// block = (32-col m-tile, h, b); 4 waves. ein1: A=y1s (global), B=xs bits (LDS xb).
// attn-LIF state in regs (C/D layout). Spikes -> LDS pb[m][n] = ein2 B-frag layout.
// ein2: A=y2s (global), B=pb. out-LIF state in regs; ushort4 store to obt[tb][m][c].
__global__ __launch_bounds__(256) void k_attn2(const unsigned short* __restrict__ xsb,
                                               const unsigned short* __restrict__ y1s,
                                               const unsigned short* __restrict__ y2s,
                                               unsigned short* __restrict__ obt) {
    __shared__ unsigned short xb[32][40];    // [m][d], stride 80B (16B-mult)
    __shared__ unsigned short pb[32][264];   // [m][n], stride 528B (16B-mult)
    const int mt0 = blockIdx.x * 32;
    const int h = blockIdx.y;
    const int b = blockIdx.z;
    const int tid = threadIdx.x;
    const int lane = tid & 63, wv = tid >> 6;
    const int quad = lane >> 4, lr = lane & 15;
    const int dt = wv >> 1, ct = wv & 1;     // ein2 / out-LIF tile for this wave

    float vat[4][2][4];                      // attn LIF state (n=wv*64+it*16+quad*4+r, m=mt0+jt*16+lr)
#pragma unroll
    for (int it = 0; it < 4; ++it)
#pragma unroll
        for (int jt = 0; jt < 2; ++jt)
#pragma unroll
            for (int r = 0; r < 4; ++r) vat[it][jt][r] = 0.f;
    float vo[4] = {0.f, 0.f, 0.f, 0.f};      // out LIF state (d=dt*16+quad*4+r, m=mt0+ct*16+lr)

    for (int t = 0; t < T_; ++t) {
        const int tb = t * B_ + b;
        // stage xs bits: xb[j][d]
#pragma unroll
        for (int i = 0; i < 4; ++i) {
            int e = tid + i * 256;
            int d = e >> 5, j = e & 31;
            xb[j][d] = xsb[((size_t)tb * C_ + h * 32 + d) * HW + mt0 + j];
        }
        __syncthreads();

        short8 bx[2];
#pragma unroll
        for (int jt = 0; jt < 2; ++jt)
            bx[jt] = *(const short8*)&xb[jt * 16 + lr][quad * 8];

        f32x4 acc[4][2];
#pragma unroll
        for (int it = 0; it < 4; ++it)
#pragma unroll
            for (int jt = 0; jt < 2; ++jt)
                acc[it][jt] = (f32x4){0.f, 0.f, 0.f, 0.f};

        const unsigned short* y1p = y1s + (size_t)(tb * NH_ + h) * 3 * 8192
                                        + (size_t)(wv * 64 + lr) * 32 + quad * 8;
#pragma unroll
        for (int s = 0; s < 3; ++s)
#pragma unroll
            for (int it = 0; it < 4; ++it) {
                short8 a = *(const short8*)(y1p + s * 8192 + it * 512);
#pragma unroll
                for (int jt = 0; jt < 2; ++jt)
                    acc[it][jt] = __builtin_amdgcn_mfma_f32_16x16x32_bf16(a, bx[jt], acc[it][jt], 0, 0, 0);
            }

        // attn LIF -> spikes into pb (ein2 B-frag layout)
#pragma unroll
        for (int it = 0; it < 4; ++it)
#pragma unroll
            for (int jt = 0; jt < 2; ++jt) {
                ushort4 sp;
#pragma unroll
                for (int r = 0; r < 4; ++r) {
                    float v = vat[it][jt][r];
                    v += (acc[it][jt][r] - v) * 0.5f;
                    bool s = (v >= 1.0f);
                    ((unsigned short*)&sp)[r] = s ? 0x3F80 : 0;
                    vat[it][jt][r] = s ? 0.f : v;
                }
                *(ushort4*)&pb[jt * 16 + lr][wv * 64 + it * 16 + quad * 4] = sp;
            }
        __syncthreads();

        // ein2: out[d][m] = y2s · pb
        f32x4 acc2 = (f32x4){0.f, 0.f, 0.f, 0.f};
        const unsigned short* y2p = y2s + (size_t)(tb * NH_ + h) * 3 * 8192
                                        + (size_t)(dt * 16 + lr) * 256 + quad * 8;
#pragma unroll
        for (int s = 0; s < 3; ++s)
#pragma unroll
            for (int k0 = 0; k0 < 256; k0 += 32) {
                short8 a2 = *(const short8*)(y2p + s * 8192 + k0);
                short8 b2 = *(const short8*)&pb[ct * 16 + lr][k0 + quad * 8];
                acc2 = __builtin_amdgcn_mfma_f32_16x16x32_bf16(a2, b2, acc2, 0, 0, 0);
            }

        // out LIF -> obt[tb][m][c] bf16 (c-contiguous ushort4)
        ushort4 ob;
#pragma unroll
        for (int r = 0; r < 4; ++r) {
            float v = vo[r];
            v += (acc2[r] - v) * 0.5f;
            bool s = (v >= 1.0f);
            ((unsigned short*)&ob)[r] = s ? 0x3F80 : 0;
            vo[r] = s ? 0.f : v;
        }
        *(ushort4*)(obt + ((size_t)tb * HW + mt0 + ct * 16 + lr) * C_
                        + h * 32 + dt * 16 + quad * 4) = ob;
        __syncthreads();   // protect xb/pb before next t
    }
}

// ---------------- K4: proj GEMM via MFMA + BN2 + residual ----------------
__global__ __launch_bounds__(256) void k_mproj(const unsigned short* __restrict__ obt,
                                               const unsigned short* __restrict__ Wp3,
                                               const float* __restrict__ g2,
                                               const float* __restrict__ b2,
                                               const float* __restrict__ x,
                                               float* __restrict__ out) {
    __shared__ short As[3][64][LDK];
    __shared__ short Bs[128][LDK];
    const int nb = blockIdx.x, mb = blockIdx.y;
    const int tid = threadIdx.x;
    const int lane = tid & 63, wave = tid >> 6;
    const int wm = wave >> 1, wn = wave & 1;
    const int quad = lane >> 4, lr = lane & 15;
    const int arow = tid >> 2, akoff = (tid & 3) * 8;
    f32x4 acc[2][4];
#pragma unroll
    for (int im = 0; im < 2; ++im)
#pragma unroll
        for (int in = 0; in < 4; ++in)
            acc[im][in] = (f32x4){0.f, 0.f, 0.f, 0.f};

    for (int k0 = 0; k0 < 384; k0 += 32) {
#pragma unroll
        for (int s = 0; s < 3; ++s) {
            short8 a = *(const short8*)(Wp3 + ((size_t)(s * 384 + mb * 64 + arow)) * 384 + k0 + akoff);
            *(short8*)&As[s][arow][akoff] = a;
        }
#pragma unroll
        for (int i = 0; i < 2; ++i) {
            int f = i * 256 + tid;
            int row = f >> 2, koff = (f & 3) * 8;
            short8 bv = *(const short8*)(obt + ((size_t)(nb * 128 + row)) * 384 + k0 + koff);
            *(short8*)&Bs[row][koff] = bv;
        }
        __syncthreads();
        short8 bf[4], af[3][2];
#pragma unroll
        for (int in = 0; in < 4; ++in)
            bf[in] = *(const short8*)&Bs[wn * 64 + in * 16 + lr][quad * 8];
#pragma unroll
        for (int s = 0; s < 3; ++s)
#pragma unroll
            for (int im = 0; im < 2; ++im)
                af[s][im] = *(const short8*)&As[s][wm * 32 + im * 16 + lr][quad * 8];
#pragma unroll
        for (int s = 0; s < 3; ++s)
#pragma unroll
            for (int im = 0; im < 2; ++im)
#pragma unroll
                for (int in = 0; in < 4; ++in)
                    acc[im][in] = __builtin_amdgcn_mfma_f32_16x16x32_bf16(af[s][im], bf[in], acc[im][in], 0, 0, 0);
        __syncthreads();
    }
    const float rs = 1.0f / sqrtf(1.0f + EPS_);
#pragma unroll
    for (int im = 0; im < 2; ++im) {
#pragma unroll
        for (int in = 0; in < 4; ++in) {
            int n_g = nb * 128 + wn * 64 + in * 16 + lr;
            int tb = n_g >> 10, hw = n_g & 1023;
#pragma unroll
            for (int r = 0; r < 4; ++r) {
                int o = mb * 64 + wm * 32 + im * 16 + quad * 4 + r;
                size_t idx = ((size_t)tb * C_ + o) * HW + hw;
                out[idx] = acc[im][in][r] * (g2[o] * rs) + b2[o] + x[idx];
            }
        }
    }
}

extern "C" void kernel_launch(void* const* d_in, const int* in_sizes, int n_in,
                              void* d_out, int out_size, void* d_ws, size_t ws_size,
                              hipStream_t stream) {
    const float* x      = (const float*)d_in[0];
    const float* Wconv  = (const float*)d_in[1];
    const float* gamma1 = (const float*)d_in[2];
    const float* beta1  = (const float*)d_in[3];
    const float* Wproj  = (const float*)d_in[4];
    const float* gamma2 = (const float*)d_in[5];
    const float* beta2  = (const float*)d_in[6];
    const float* frx    = (const float*)d_in[7];
    const float* fra    = (const float*)d_in[8];
    float* out = (float*)d_out;

    unsigned short* ws16 = (unsigned short*)d_ws;
    unsigned short* Bc  = ws16;                 // 4096*1536 = 6,291,456  (aliased by obt later)
    unsigned short* obt = ws16;                 // safe: Bc consumed by k_mconv before k_attn2 writes
    unsigned short* Wc3 = ws16 + 6291456;       // 3,538,944
    unsigned short* Wp3 = ws16 + 9830400;       // 442,368
    unsigned short* xsb = ws16 + 10272768;      // 6,291,456
    unsigned short* y1s = ws16 + 16564224;      // 4,718,592
    unsigned short* y2s = ws16 + 21282816;      // 4,718,592  (end 26,001,408 u16 = 52.0 MB)

    k_wsplit<<<5184, 256, 0, stream>>>(Wconv, Wproj, Wc3, Wp3);
    k_lif_im2col<<<1536, 256, 0, stream>>>(x, Bc, xsb);
    k_mconv<<<dim3(32, 12), 256, 0, stream>>>(Bc, Wc3, gamma1, beta1, frx, fra, y1s, y2s);
    k_attn2<<<dim3(32, 12, 4), 256, 0, stream>>>(xsb, y1s, y2s, obt);
    k_mproj<<<dim3(128, 6), 256, 0, stream>>>(obt, Wp3, gamma2, beta2, x, out);
}

// Round 4
// 268.449 us; speedup vs baseline: 1.4534x; 1.0259x over previous
//
#include <hip/hip_runtime.h>
#include <hip/hip_bf16.h>
#include <math.h>

// R4: k_attn2 restructured for latency hiding:
//   - xs bits for all 4 timesteps staged in LDS once (no per-t staging barrier)
//   - pb (spike) double-buffered -> exactly 1 barrier per t (was 3)
//   - all 36 y1/y2 fragments preloaded per t into regs (batched load stream);
//     ay survives the barrier so ein2 has zero load latency on its critical path
// Other kernels unchanged from R3 (they passed, none in top-5).

typedef __attribute__((ext_vector_type(8))) short short8;
typedef __attribute__((ext_vector_type(4))) float f32x4;

#define T_ 4
#define B_ 4
#define C_ 384
#define HW 1024
#define NH_ 12
#define Np_ 256
#define EPS_ 1e-5f
#define LDK 56

static __device__ __forceinline__ unsigned short f2bf(float f) {
    __hip_bfloat16 h = __float2bfloat16(f);
    return *reinterpret_cast<unsigned short*>(&h);
}
static __device__ __forceinline__ float bf2f(unsigned short u) {
    __hip_bfloat16 h = *reinterpret_cast<__hip_bfloat16*>(&u);
    return __bfloat162float(h);
}
static __device__ __forceinline__ void split3(float w, unsigned short& u0,
                                              unsigned short& u1, unsigned short& u2) {
    u0 = f2bf(w);  float f0 = bf2f(u0);
    float r1 = w - f0;
    u1 = f2bf(r1); float f1 = bf2f(u1);
    u2 = f2bf(r1 - f1);
}

// ---------------- K0: weight 3-way bf16 split ----------------
__global__ __launch_bounds__(256) void k_wsplit(const float* __restrict__ Wc,
                                                const float* __restrict__ Wp,
                                                unsigned short* __restrict__ Wc3,
                                                unsigned short* __restrict__ Wp3) {
    const int NC = 768 * 1536;
    const int NP = 384 * 384;
    int i = blockIdx.x * 256 + threadIdx.x;
    float w; unsigned short* dst; int idx, plane;
    if (i < NC) { w = Wc[i]; dst = Wc3; idx = i; plane = NC; }
    else {
        int j = i - NC;
        if (j >= NP) return;
        w = Wp[j]; dst = Wp3; idx = j; plane = NP;
    }
    unsigned short u0, u1, u2;
    split3(w, u0, u1, u2);
    dst[idx] = u0; dst[plane + idx] = u1; dst[2 * plane + idx] = u2;
}

// ---------------- K1: LIF(x) fused with im2col -> Bc[n][k] bf16, + xsb[tb][c][hw] bf16 ----
__global__ __launch_bounds__(256) void k_lif_im2col(const float* __restrict__ x,
                                                    unsigned short* __restrict__ Bc,
                                                    unsigned short* __restrict__ xsb) {
    int gt = blockIdx.x * 256 + threadIdx.x;
    int pw = gt & 15, ph = (gt >> 4) & 15;
    int v = gt >> 8;
    int c = v % 384, b = v / 384;
    float v00 = 0.f, v01 = 0.f, v10 = 0.f, v11 = 0.f;
    const size_t xrow = ((size_t)b * C_ + c) * HW + (size_t)(2 * ph) * 32 + 2 * pw;
#pragma unroll
    for (int t = 0; t < T_; ++t) {
        const float* px = x + (size_t)t * (B_ * C_ * HW) + xrow;
        float2 r0 = *(const float2*)px;
        float2 r1 = *(const float2*)(px + 32);
        v00 += (r0.x - v00) * 0.5f;
        v01 += (r0.y - v01) * 0.5f;
        v10 += (r1.x - v10) * 0.5f;
        v11 += (r1.y - v11) * 0.5f;
        ushort4 s;
        s.x = (v00 >= 1.f) ? 0x3F80 : 0; if (v00 >= 1.f) v00 = 0.f;
        s.y = (v01 >= 1.f) ? 0x3F80 : 0; if (v01 >= 1.f) v01 = 0.f;
        s.z = (v10 >= 1.f) ? 0x3F80 : 0; if (v10 >= 1.f) v10 = 0.f;
        s.w = (v11 >= 1.f) ? 0x3F80 : 0; if (v11 >= 1.f) v11 = 0.f;
        int tb = t * B_ + b;
        int n = tb * 256 + ph * 16 + pw;
        *(ushort4*)(Bc + (size_t)n * 1536 + 4 * c) = s;
        size_t xo = ((size_t)tb * C_ + c) * HW + (size_t)(2 * ph) * 32 + 2 * pw;
        ushort2 w0 = {s.x, s.y}, w1 = {s.z, s.w};
        *(ushort2*)(xsb + xo) = w0;
        *(ushort2*)(xsb + xo + 32) = w1;
    }
}

// ---------------- K2: conv GEMM via MFMA; epilogue emits scaled 3-split y1s/y2s ----------
__global__ __launch_bounds__(256) void k_mconv(const unsigned short* __restrict__ Bc,
                                               const unsigned short* __restrict__ Wc3,
                                               const float* __restrict__ g1,
                                               const float* __restrict__ b1,
                                               const float* __restrict__ frx,
                                               const float* __restrict__ fra,
                                               unsigned short* __restrict__ y1s,
                                               unsigned short* __restrict__ y2s) {
    __shared__ short As[3][64][LDK];
    __shared__ short Bs[128][LDK];
    const int nb = blockIdx.x, mb = blockIdx.y;
    const int tid = threadIdx.x;
    const int lane = tid & 63, wave = tid >> 6;
    const int wm = wave >> 1, wn = wave & 1;
    const int quad = lane >> 4, lr = lane & 15;
    const int arow = tid >> 2, akoff = (tid & 3) * 8;
    f32x4 acc[2][4];
#pragma unroll
    for (int im = 0; im < 2; ++im)
#pragma unroll
        for (int in = 0; in < 4; ++in)
            acc[im][in] = (f32x4){0.f, 0.f, 0.f, 0.f};

    for (int k0 = 0; k0 < 1536; k0 += 32) {
#pragma unroll
        for (int s = 0; s < 3; ++s) {
            short8 a = *(const short8*)(Wc3 + ((size_t)(s * 768 + mb * 64 + arow)) * 1536 + k0 + akoff);
            *(short8*)&As[s][arow][akoff] = a;
        }
#pragma unroll
        for (int i = 0; i < 2; ++i) {
            int f = i * 256 + tid;
            int row = f >> 2, koff = (f & 3) * 8;
            short8 bv = *(const short8*)(Bc + ((size_t)(nb * 128 + row)) * 1536 + k0 + koff);
            *(short8*)&Bs[row][koff] = bv;
        }
        __syncthreads();
        short8 bf[4], af[3][2];
#pragma unroll
        for (int in = 0; in < 4; ++in)
            bf[in] = *(const short8*)&Bs[wn * 64 + in * 16 + lr][quad * 8];
#pragma unroll
        for (int s = 0; s < 3; ++s)
#pragma unroll
            for (int im = 0; im < 2; ++im)
                af[s][im] = *(const short8*)&As[s][wm * 32 + im * 16 + lr][quad * 8];
#pragma unroll
        for (int s = 0; s < 3; ++s)
#pragma unroll
            for (int im = 0; im < 2; ++im)
#pragma unroll
                for (int in = 0; in < 4; ++in)
                    acc[im][in] = __builtin_amdgcn_mfma_f32_16x16x32_bf16(af[s][im], bf[in], acc[im][in], 0, 0, 0);
        __syncthreads();
    }
    const float rs = 1.0f / sqrtf(1.0f + EPS_);
    const int h = mb;
    const float scl = (wm == 0) ? (1.0f / sqrtf(frx[h] * 32.0f))
                                : (1.0f / sqrtf(fra[h] * 256.0f));
    unsigned short* dst = (wm == 0) ? y1s : y2s;
#pragma unroll
    for (int im = 0; im < 2; ++im) {
#pragma unroll
        for (int in = 0; in < 4; ++in) {
            int n_g = nb * 128 + wn * 64 + in * 16 + lr;
            int tb = n_g >> 8, pn = n_g & 255;
            size_t base = (size_t)(tb * NH_ + h) * 3 * 8192;
            ushort4 o0, o1, o2;
#pragma unroll
            for (int r = 0; r < 4; ++r) {
                int oc = mb * 64 + wm * 32 + im * 16 + quad * 4 + r;
                float val = (acc[im][in][r] * (g1[oc] * rs) + b1[oc]) * scl;
                unsigned short u0, u1, u2;
                split3(val, u0, u1, u2);
                ((unsigned short*)&o0)[r] = u0;
                ((unsigned short*)&o1)[r] = u1;
                ((unsigned short*)&o2)[r] = u2;
            }
            int dd = im * 16 + quad * 4;
            if (wm == 0) {
                *(ushort4*)&dst[base + 0 * 8192 + (size_t)pn * 32 + dd] = o0;
                *(ushort4*)&dst[base + 1 * 8192 + (size_t)pn * 32 + dd] = o1;
                *(ushort4*)&dst[base + 2 * 8192 + (size_t)pn * 32 + dd] = o2;
            } else {
#pragma unroll
                for (int r = 0; r < 4; ++r) {
                    dst[base + 0 * 8192 + (size_t)(dd + r) * 256 + pn] = ((unsigned short*)&o0)[r];
                    dst[base + 1 * 8192 + (size_t)(dd + r) * 256 + pn] = ((unsigned short*)&o1)[r];
                    dst[base + 2 * 8192 + (size_t)(dd + r) * 256 + pn] = ((unsigned short*)&o2)[r];
                }
            }
        }
    }
}

// ---------------- K3: fused attention, all-MFMA, 1 barrier per t ----------------
__global__ __launch_bounds__(256, 2) void k_attn2(const unsigned short* __restrict__ xsb,
                                                  const unsigned short* __restrict__ y1s,
                                                  const unsigned short* __restrict__ y2s,
                                                  unsigned short* __restrict__ obt) {
    __shared__ unsigned short xb[4][32][40];     // [t][m][d] : 10,240 B
    __shared__ unsigned short pb[2][32][264];    // [buf][m][n] : 33,792 B  (total 44 KB)
    const int mt0 = blockIdx.x * 32;
    const int h = blockIdx.y;
    const int b = blockIdx.z;
    const int tid = threadIdx.x;
    const int lane = tid & 63, wv = tid >> 6;
    const int quad = lane >> 4, lr = lane & 15;
    const int dt = wv >> 1, ct = wv & 1;

    // stage xs bits for ALL 4 timesteps (coalesced over j)
#pragma unroll
    for (int i = 0; i < 16; ++i) {
        int e = tid + i * 256;
        int j = e & 31, d = (e >> 5) & 31, t = e >> 10;
        xb[t][j][d] = xsb[((size_t)((t * B_ + b) * C_) + h * 32 + d) * HW + mt0 + j];
    }
    __syncthreads();

    float vat[4][2][4];
#pragma unroll
    for (int it = 0; it < 4; ++it)
#pragma unroll
        for (int jt = 0; jt < 2; ++jt)
#pragma unroll
            for (int r = 0; r < 4; ++r) vat[it][jt][r] = 0.f;
    float vo[4] = {0.f, 0.f, 0.f, 0.f};

    for (int t = 0; t < T_; ++t) {
        const int tb = t * B_ + b;
        const size_t slab = (size_t)(tb * NH_ + h) * 3 * 8192;

        // ---- batched fragment preload (36 independent 16B loads) ----
        short8 af[3][4];
        const unsigned short* y1p = y1s + slab + (size_t)(wv * 64 + lr) * 32 + quad * 8;
#pragma unroll
        for (int s = 0; s < 3; ++s)
#pragma unroll
            for (int it = 0; it < 4; ++it)
                af[s][it] = *(const short8*)(y1p + s * 8192 + it * 512);
        short8 ay[3][8];
        const unsigned short* y2p = y2s + slab + (size_t)(dt * 16 + lr) * 256 + quad * 8;
#pragma unroll
        for (int s = 0; s < 3; ++s)
#pragma unroll
            for (int kt = 0; kt < 8; ++kt)
                ay[s][kt] = *(const short8*)(y2p + s * 8192 + kt * 32);

        short8 bx[2];
#pragma unroll
        for (int jt = 0; jt < 2; ++jt)
            bx[jt] = *(const short8*)&xb[t][jt * 16 + lr][quad * 8];

        // ---- ein1 ----
        f32x4 acc[4][2];
#pragma unroll
        for (int it = 0; it < 4; ++it)
#pragma unroll
            for (int jt = 0; jt < 2; ++jt)
                acc[it][jt] = (f32x4){0.f, 0.f, 0.f, 0.f};
#pragma unroll
        for (int s = 0; s < 3; ++s)
#pragma unroll
            for (int it = 0; it < 4; ++it)
#pragma unroll
                for (int jt = 0; jt < 2; ++jt)
                    acc[it][jt] = __builtin_amdgcn_mfma_f32_16x16x32_bf16(af[s][it], bx[jt], acc[it][jt], 0, 0, 0);

        // ---- attn LIF -> spikes into pb[t&1] (ein2 B-frag layout) ----
#pragma unroll
        for (int it = 0; it < 4; ++it)
#pragma unroll
            for (int jt = 0; jt < 2; ++jt) {
                ushort4 sp;
#pragma unroll
                for (int r = 0; r < 4; ++r) {
                    float v = vat[it][jt][r];
                    v += (acc[it][jt][r] - v) * 0.5f;
                    bool s = (v >= 1.0f);
                    ((unsigned short*)&sp)[r] = s ? 0x3F80 : 0;
                    vat[it][jt][r] = s ? 0.f : v;
                }
                *(ushort4*)&pb[t & 1][jt * 16 + lr][wv * 64 + it * 16 + quad * 4] = sp;
            }
        __syncthreads();   // the ONLY barrier per t

        // ---- ein2 (A-operands already in regs) ----
        f32x4 acc2 = (f32x4){0.f, 0.f, 0.f, 0.f};
#pragma unroll
        for (int s = 0; s < 3; ++s)
#pragma unroll
            for (int kt = 0; kt < 8; ++kt) {
                short8 b2 = *(const short8*)&pb[t & 1][ct * 16 + lr][kt * 32 + quad * 8];
                acc2 = __builtin_amdgcn_mfma_f32_16x16x32_bf16(ay[s][kt], b2, acc2, 0, 0, 0);
            }

        // ---- out LIF -> obt[tb][m][c] ----
        ushort4 ob;
#pragma unroll
        for (int r = 0; r < 4; ++r) {
            float v = vo[r];
            v += (acc2[r] - v) * 0.5f;
            bool s = (v >= 1.0f);
            ((unsigned short*)&ob)[r] = s ? 0x3F80 : 0;
            vo[r] = s ? 0.f : v;
        }
        *(ushort4*)(obt + ((size_t)tb * HW + mt0 + ct * 16 + lr) * C_
                        + h * 32 + dt * 16 + quad * 4) = ob;
    }
}

// ---------------- K4: proj GEMM via MFMA + BN2 + residual ----------------
__global__ __launch_bounds__(256) void k_mproj(const unsigned short* __restrict__ obt,
                                               const unsigned short* __restrict__ Wp3,
                                               const float* __restrict__ g2,
                                               const float* __restrict__ b2,
                                               const float* __restrict__ x,
                                               float* __restrict__ out) {
    __shared__ short As[3][64][LDK];
    __shared__ short Bs[128][LDK];
    const int nb = blockIdx.x, mb = blockIdx.y;
    const int tid = threadIdx.x;
    const int lane = tid & 63, wave = tid >> 6;
    const int wm = wave >> 1, wn = wave & 1;
    const int quad = lane >> 4, lr = lane & 15;
    const int arow = tid >> 2, akoff = (tid & 3) * 8;
    f32x4 acc[2][4];
#pragma unroll
    for (int im = 0; im < 2; ++im)
#pragma unroll
        for (int in = 0; in < 4; ++in)
            acc[im][in] = (f32x4){0.f, 0.f, 0.f, 0.f};

    for (int k0 = 0; k0 < 384; k0 += 32) {
#pragma unroll
        for (int s = 0; s < 3; ++s) {
            short8 a = *(const short8*)(Wp3 + ((size_t)(s * 384 + mb * 64 + arow)) * 384 + k0 + akoff);
            *(short8*)&As[s][arow][akoff] = a;
        }
#pragma unroll
        for (int i = 0; i < 2; ++i) {
            int f = i * 256 + tid;
            int row = f >> 2, koff = (f & 3) * 8;
            short8 bv = *(const short8*)(obt + ((size_t)(nb * 128 + row)) * 384 + k0 + koff);
            *(short8*)&Bs[row][koff] = bv;
        }
        __syncthreads();
        short8 bf[4], af[3][2];
#pragma unroll
        for (int in = 0; in < 4; ++in)
            bf[in] = *(const short8*)&Bs[wn * 64 + in * 16 + lr][quad * 8];
#pragma unroll
        for (int s = 0; s < 3; ++s)
#pragma unroll
            for (int im = 0; im < 2; ++im)
                af[s][im] = *(const short8*)&As[s][wm * 32 + im * 16 + lr][quad * 8];
#pragma unroll
        for (int s = 0; s < 3; ++s)
#pragma unroll
            for (int im = 0; im < 2; ++im)
#pragma unroll
                for (int in = 0; in < 4; ++in)
                    acc[im][in] = __builtin_amdgcn_mfma_f32_16x16x32_bf16(af[s][im], bf[in], acc[im][in], 0, 0, 0);
        __syncthreads();
    }
    const float rs = 1.0f / sqrtf(1.0f + EPS_);
#pragma unroll
    for (int im = 0; im < 2; ++im) {
#pragma unroll
        for (int in = 0; in < 4; ++in) {
            int n_g = nb * 128 + wn * 64 + in * 16 + lr;
            int tb = n_g >> 10, hw = n_g & 1023;
#pragma unroll
            for (int r = 0; r < 4; ++r) {
                int o = mb * 64 + wm * 32 + im * 16 + quad * 4 + r;
                size_t idx = ((size_t)tb * C_ + o) * HW + hw;
                out[idx] = acc[im][in][r] * (g2[o] * rs) + b2[o] + x[idx];
            }
        }
    }
}

extern "C" void kernel_launch(void* const* d_in, const int* in_sizes, int n_in,
                              void* d_out, int out_size, void* d_ws, size_t ws_size,
                              hipStream_t stream) {
    const float* x      = (const float*)d_in[0];
    const float* Wconv  = (const float*)d_in[1];
    const float* gamma1 = (const float*)d_in[2];
    const float* beta1  = (const float*)d_in[3];
    const float* Wproj  = (const float*)d_in[4];
    const float* gamma2 = (const float*)d_in[5];
    const float* beta2  = (const float*)d_in[6];
    const float* frx    = (const float*)d_in[7];
    const float* fra    = (const float*)d_in[8];
    float* out = (float*)d_out;

    unsigned short* ws16 = (unsigned short*)d_ws;
    unsigned short* Bc  = ws16;                 // 6,291,456 u16 (aliased by obt after k_mconv)
    unsigned short* obt = ws16;
    unsigned short* Wc3 = ws16 + 6291456;       // 3,538,944
    unsigned short* Wp3 = ws16 + 9830400;       // 442,368
    unsigned short* xsb = ws16 + 10272768;      // 6,291,456
    unsigned short* y1s = ws16 + 16564224;      // 4,718,592
    unsigned short* y2s = ws16 + 21282816;      // 4,718,592

    k_wsplit<<<5184, 256, 0, stream>>>(Wconv, Wproj, Wc3, Wp3);
    k_lif_im2col<<<1536, 256, 0, stream>>>(x, Bc, xsb);
    k_mconv<<<dim3(32, 12), 256, 0, stream>>>(Bc, Wc3, gamma1, beta1, frx, fra, y1s, y2s);
    k_attn2<<<dim3(32, 12, 4), 256, 0, stream>>>(xsb, y1s, y2s, obt);
    k_mproj<<<dim3(128, 6), 256, 0, stream>>>(obt, Wp3, gamma2, beta2, x, out);
}